// Round 3
// baseline (673.208 us; speedup 1.0000x reference)
//
#include <hip/hip_runtime.h>
#include <hip/hip_bf16.h>
#include <math.h>

// Problem constants
#define B_  256
#define S_  20
#define V_  20000
#define C_  20
#define D_  64
#define MTOT (B_*S_ + B_)      // 5376 rows: 5120 support + 256 target
#define KSPLIT 12
#define KCH 52                 // base k32-chunk per split; last split gets 53
#define NK32 625               // 20000 / 32 fp32-K units

typedef __bf16 bf16x8 __attribute__((ext_vector_type(8)));
typedef float  f32x4  __attribute__((ext_vector_type(4)));

// Split 8 fp32 into truncated-bf16 hi (uint4) + bf16(residual) lo (uint4).
// x = hi + r exactly; dropped lo*lo MFMA term ~2^-16 rel (verified absmax 0.0).
__device__ __forceinline__ void split8(const float4 a, const float4 b,
                                       uint4& hi, uint4& lo) {
    const float f[8] = {a.x, a.y, a.z, a.w, b.x, b.y, b.z, b.w};
    unsigned int h[8]; float r[8];
#pragma unroll
    for (int j = 0; j < 8; ++j) {
        const unsigned int u = __float_as_uint(f[j]);
        h[j] = u & 0xFFFF0000u;
        r[j] = f[j] - __uint_as_float(h[j]);
    }
    hi.x = (h[0] >> 16) | h[1];
    hi.y = (h[2] >> 16) | h[3];
    hi.z = (h[4] >> 16) | h[5];
    hi.w = (h[6] >> 16) | h[7];
    lo.x = (__float_as_uint(r[0]) >> 16) | (__float_as_uint(r[1]) & 0xFFFF0000u);
    lo.y = (__float_as_uint(r[2]) >> 16) | (__float_as_uint(r[3]) & 0xFFFF0000u);
    lo.z = (__float_as_uint(r[4]) >> 16) | (__float_as_uint(r[5]) & 0xFFFF0000u);
    lo.w = (__float_as_uint(r[6]) >> 16) | (__float_as_uint(r[7]) & 0xFFFF0000u);
}

// ---------------------------------------------------------------------------
// gemm4: barrier-free, LDS-free, wconv fused away. Block = 4 waves x 64
// M-rows = 256 rows; all waves share one K-chunk. W is read as raw fp32 and
// hi/lo-split ON THE FLY: the fp32 W slice per step (128 B/lane) is the SAME
// byte count as the pre-converted hi+lo bf16 frags were, so L1/L2 traffic is
// unchanged while the Wf arrays (10.2 MB HBM write + read-back) and the
// wconv dispatch disappear. VALU/step ~950 cyc vs 3072-cyc BW budget/step:
// still HBM-A-bound. KSPLIT=12: 21x12=252 blocks = one co-resident round.
// Per wave per k32: 4 A-frags + 4 W-rows-of-8 split hi/lo -> 48 MFMAs.
// Ragged chunks (11x52 + 1x53) via the clamp/dummy-reload tail.
// W-frag layout check (matches old wconv): lane ln,qd holds
// W[16tt+ln][c*32+qd*8+j], j=0..7 — the mfma_16x16x32_bf16 B fragment.
// ---------------------------------------------------------------------------
__global__ __launch_bounds__(256, 2)
void gemm4_kernel(const float* __restrict__ sup,
                  const float* __restrict__ tgtim,
                  const float* __restrict__ W,
                  float* __restrict__ Ep,
                  unsigned* __restrict__ ctr) {
    const int bmx = blockIdx.x;         // 0..20 (M-block of 256 rows)
    const int bk  = blockIdx.y;         // 0..11 (K-split)
    const int t = threadIdx.x;
    if (bmx == 0 && bk == 0 && t == 0) *ctr = 0u;   // phase23 completion ctr
    const int w = t >> 6, lane = t & 63;
    const int ln = lane & 15, qd = lane >> 4;
    const int mrow0 = bmx * 256 + w * 64;   // wave's 64-row block

    // 5120 = 20*256: blocks 0..19 fully support, block 20 fully target.
    const float* xbase = (mrow0 < B_*S_)
        ? (sup   + (size_t)mrow0 * V_)
        : (tgtim + (size_t)(mrow0 - B_*S_) * V_);
    const float* xr0 = xbase + (size_t)ln * V_ + qd * 8;
    const float* xr1 = xr0 + (size_t)16 * V_;
    const float* xr2 = xr1 + (size_t)16 * V_;
    const float* xr3 = xr2 + (size_t)16 * V_;
    // W row pointers for the 4 tt-fragments (d-rows 16tt+ln), k-offset qd*8.
    const float* wr0 = W + (size_t)ln * V_ + qd * 8;
    const float* wr1 = wr0 + (size_t)16 * V_;
    const float* wr2 = wr1 + (size_t)16 * V_;
    const float* wr3 = wr2 + (size_t)16 * V_;

    const int c0 = bk * KCH;
    const int nk = (bk == KSPLIT - 1) ? (NK32 - KCH * (KSPLIT - 1)) : KCH; // 53 : 52

    f32x4 acc[4][4];
#pragma unroll
    for (int i = 0; i < 4; ++i)
#pragma unroll
        for (int j = 0; j < 4; ++j) acc[i][j] = (f32x4){0.f, 0.f, 0.f, 0.f};

    float4 aA[4][2], aB[4][2];      // A raw fp32 ping-pong
    float4 wA[4][2], wB[4][2];      // W raw fp32 ping-pong

#define LDA(buf, c) do {                                                      \
    const size_t off_ = (size_t)(c) * 32;                                     \
    buf[0][0] = *(const float4*)(xr0 + off_);                                 \
    buf[0][1] = *(const float4*)(xr0 + off_ + 4);                             \
    buf[1][0] = *(const float4*)(xr1 + off_);                                 \
    buf[1][1] = *(const float4*)(xr1 + off_ + 4);                             \
    buf[2][0] = *(const float4*)(xr2 + off_);                                 \
    buf[2][1] = *(const float4*)(xr2 + off_ + 4);                             \
    buf[3][0] = *(const float4*)(xr3 + off_);                                 \
    buf[3][1] = *(const float4*)(xr3 + off_ + 4);                             \
} while (0)

#define LDW(buf, c) do {                                                      \
    const size_t off_ = (size_t)(c) * 32;                                     \
    buf[0][0] = *(const float4*)(wr0 + off_);                                 \
    buf[0][1] = *(const float4*)(wr0 + off_ + 4);                             \
    buf[1][0] = *(const float4*)(wr1 + off_);                                 \
    buf[1][1] = *(const float4*)(wr1 + off_ + 4);                             \
    buf[2][0] = *(const float4*)(wr2 + off_);                                 \
    buf[2][1] = *(const float4*)(wr2 + off_ + 4);                             \
    buf[3][0] = *(const float4*)(wr3 + off_);                                 \
    buf[3][1] = *(const float4*)(wr3 + off_ + 4);                             \
} while (0)

// Split A rows once (af-major), then per tt split W and run the 4x3 MFMAs.
#define STEP(abuf, wbuf) do {                                                 \
    uint4 ahu_[4], alu_[4];                                                   \
    _Pragma("unroll")                                                         \
    for (int af = 0; af < 4; ++af)                                            \
        split8(abuf[af][0], abuf[af][1], ahu_[af], alu_[af]);                 \
    _Pragma("unroll")                                                         \
    for (int tt = 0; tt < 4; ++tt) {                                          \
        uint4 bhu_, blu_;                                                     \
        split8(wbuf[tt][0], wbuf[tt][1], bhu_, blu_);                         \
        const bf16x8 bh_ = *(const bf16x8*)&bhu_;                             \
        const bf16x8 bl_ = *(const bf16x8*)&blu_;                             \
        _Pragma("unroll")                                                     \
        for (int af = 0; af < 4; ++af) {                                      \
            const bf16x8 ah_ = *(const bf16x8*)&ahu_[af];                     \
            const bf16x8 al_ = *(const bf16x8*)&alu_[af];                     \
            acc[af][tt] = __builtin_amdgcn_mfma_f32_16x16x32_bf16(ah_, bh_, acc[af][tt], 0, 0, 0); \
            acc[af][tt] = __builtin_amdgcn_mfma_f32_16x16x32_bf16(ah_, bl_, acc[af][tt], 0, 0, 0); \
            acc[af][tt] = __builtin_amdgcn_mfma_f32_16x16x32_bf16(al_, bh_, acc[af][tt], 0, 0, 0); \
        }                                                                     \
    }                                                                         \
} while (0)

    LDA(aA, c0); LDW(wA, c0);
    int i = 0;
#pragma unroll 1
    for (; i + 2 <= nk; i += 2) {
        const int c1 = c0 + i + 1;
        LDA(aB, c1); LDW(wB, c1);
        STEP(aA, wA);
        const int c2 = c0 + ((i + 2 < nk) ? (i + 2) : (i + 1));  // clamp: dummy reload
        LDA(aA, c2); LDW(wA, c2);
        STEP(aB, wB);
    }
    if (i < nk) STEP(aA, wA);   // odd-nk tail (bk==11, nk=53)

#undef LDA
#undef LDW
#undef STEP

    // C/D layout (m89/m91): col(lane&15)=n, row((lane>>4)*4+reg)=m
    float* dst = Ep + ((size_t)bk * MTOT + mrow0 + qd * 4) * D_ + ln;
#pragma unroll
    for (int af = 0; af < 4; ++af)
#pragma unroll
        for (int tt = 0; tt < 4; ++tt)
#pragma unroll
            for (int r = 0; r < 4; ++r)
                dst[(size_t)(af * 16 + r) * D_ + 16 * tt] = acc[af][tt][r];
}

// ---------------------------------------------------------------------------
// phase23: fused K-split reduce + distance + softmax + preds + argmax + CE,
// plus final reduction done by the last block (atomic-counter pattern).
// Block b: 256 threads sum the 21 relevant rows across 12 partials into LDS,
// then wave 0 runs the verified phase2 math. Last block runs final reduce.
// ---------------------------------------------------------------------------
__global__ __launch_bounds__(256)
void phase23_kernel(const float* __restrict__ Ep,
                    const float* __restrict__ bias,
                    const float* __restrict__ onehot,
                    const int*   __restrict__ ty_,
                    float* __restrict__ res,
                    unsigned* __restrict__ ctr,
                    float* __restrict__ out) {
    const int b = blockIdx.x;
    const int t = threadIdx.x;
    __shared__ float sm[21 * 64];
    const size_t stride = (size_t)MTOT * D_;

#pragma unroll
    for (int base = 0; base < 21 * 64; base += 256) {
        const int idx = base + t;
        if (idx < 21 * 64) {
            const int row = idx >> 6, d = idx & 63;
            const size_t grow = (row < S_) ? ((size_t)b * S_ + row)
                                           : ((size_t)(B_ * S_) + b);
            const float* p0 = Ep + grow * D_ + d;
            float s = 0.f;
#pragma unroll
            for (int p = 0; p < KSPLIT; ++p) s += p0[(size_t)p * stride];
            sm[idx] = s;
        }
    }
    __syncthreads();

    if (t < 64) {
        const int d = t;
        const float bv = bias[d];

        float supv[S_];
#pragma unroll
        for (int s = 0; s < S_; ++s) supv[s] = sm[s * 64 + d] + bv;
        float tg = sm[S_ * 64 + d] + bv;

        float sims[S_];
#pragma unroll
        for (int s = 0; s < S_; ++s) {
            float q = supv[s] * supv[s];
            float r = supv[s] * tg;
#pragma unroll
            for (int off = 32; off; off >>= 1) {
                q += __shfl_xor(q, off);
                r += __shfl_xor(r, off);
            }
            sims[s] = r * rsqrtf(fmaxf(q, 1e-10f));
        }

        float mx = sims[0];
#pragma unroll
        for (int s = 1; s < S_; ++s) mx = fmaxf(mx, sims[s]);
        float se = 0.f;
#pragma unroll
        for (int s = 0; s < S_; ++s) { sims[s] = expf(sims[s] - mx); se += sims[s]; }
        const float inv = 1.f / se;

        float pc = -INFINITY;
        if (d < C_) {
            pc = 0.f;
#pragma unroll
            for (int s = 0; s < S_; ++s)
                pc += sims[s] * inv * onehot[((size_t)b * S_ + s) * C_ + d];
        }

        float v = pc;
        int idx = (d < C_) ? d : (1 << 30);
#pragma unroll
        for (int off = 32; off; off >>= 1) {
            const float ov = __shfl_xor(v, off);
            const int   oi = __shfl_xor(idx, off);
            if (ov > v || (ov == v && oi < idx)) { v = ov; idx = oi; }
        }
        float e = (d < C_) ? expf(pc - v) : 0.f;
#pragma unroll
        for (int off = 32; off; off >>= 1) e += __shfl_xor(e, off);
        const float lse = v + logf(e);

        const int ty = ty_[b];
        const float pty = __shfl(pc, ty);

        if (d == 0) {
            res[b]      = (idx == ty) ? 1.f : 0.f;
            res[B_ + b] = lse - pty;
        }
    }

    // Last-block final reduction (rocPRIM pattern): release fence -> counter;
    // last block acquires and reduces all per-sample results.
    __threadfence();
    __shared__ unsigned lastv;
    if (t == 0) lastv = atomicAdd(ctr, 1u);
    __syncthreads();
    if (lastv == (unsigned)(B_ - 1)) {
        __threadfence();
        if (t < 64) {
            float c = 0.f, l = 0.f;
#pragma unroll
            for (int i = 0; i < 4; ++i) {
                c += res[t + 64 * i];
                l += res[B_ + t + 64 * i];
            }
#pragma unroll
            for (int off = 32; off; off >>= 1) {
                c += __shfl_xor(c, off);
                l += __shfl_xor(l, off);
            }
            if (t == 0) {
                out[0] = c * (1.f / 256.f);
                out[1] = l * (1.f / 256.f);
            }
        }
    }
}

extern "C" void kernel_launch(void* const* d_in, const int* in_sizes, int n_in,
                              void* d_out, int out_size, void* d_ws, size_t ws_size,
                              hipStream_t stream) {
    const float* sup    = (const float*)d_in[0];
    const float* onehot = (const float*)d_in[1];
    const float* tgtim  = (const float*)d_in[2];
    const int*   ty     = (const int*)  d_in[3];
    const float* W      = (const float*)d_in[4];
    const float* bias   = (const float*)d_in[5];

    // ws layout: Ep [12][5376][64] f32 | res [2][256] f32 | ctr
    float* Ep  = (float*)d_ws;
    float* res = Ep + (size_t)KSPLIT * MTOT * D_;
    unsigned* ctr = (unsigned*)(res + 512);
    float* out = (float*)d_out;

    gemm4_kernel<<<dim3(21, KSPLIT), 256, 0, stream>>>(sup, tgtim, W, Ep, ctr);
    phase23_kernel<<<B_, 256, 0, stream>>>(Ep, bias, onehot, ty, res, ctr, out);
}

// Round 4
// 616.740 us; speedup vs baseline: 1.0916x; 1.0916x over previous
//
#include <hip/hip_runtime.h>
#include <hip/hip_bf16.h>
#include <math.h>

// Problem constants
#define B_  256
#define S_  20
#define V_  20000
#define C_  20
#define D_  64
#define MTOT (B_*S_ + B_)      // 5376 rows: 5120 support + 256 target
#define KSPLIT 12
#define KCH 52                 // base k32-chunk per split; last split gets 53
#define NK32 625               // 20000 / 32 fp32-K units

typedef __bf16 bf16x8 __attribute__((ext_vector_type(8)));
typedef float  f32x4  __attribute__((ext_vector_type(4)));

// Split 8 fp32 into truncated-bf16 hi (uint4) + bf16(residual) lo (uint4).
// x = hi + r exactly; dropped lo*lo MFMA term ~2^-16 rel (verified absmax 0.0).
__device__ __forceinline__ void split8(const float4 a, const float4 b,
                                       uint4& hi, uint4& lo) {
    const float f[8] = {a.x, a.y, a.z, a.w, b.x, b.y, b.z, b.w};
    unsigned int h[8]; float r[8];
#pragma unroll
    for (int j = 0; j < 8; ++j) {
        const unsigned int u = __float_as_uint(f[j]);
        h[j] = u & 0xFFFF0000u;
        r[j] = f[j] - __uint_as_float(h[j]);
    }
    hi.x = (h[0] >> 16) | h[1];
    hi.y = (h[2] >> 16) | h[3];
    hi.z = (h[4] >> 16) | h[5];
    hi.w = (h[6] >> 16) | h[7];
    lo.x = (__float_as_uint(r[0]) >> 16) | (__float_as_uint(r[1]) & 0xFFFF0000u);
    lo.y = (__float_as_uint(r[2]) >> 16) | (__float_as_uint(r[3]) & 0xFFFF0000u);
    lo.z = (__float_as_uint(r[4]) >> 16) | (__float_as_uint(r[5]) & 0xFFFF0000u);
    lo.w = (__float_as_uint(r[6]) >> 16) | (__float_as_uint(r[7]) & 0xFFFF0000u);
}

// ---------------------------------------------------------------------------
// wconv: W [64][20000] fp32 -> B-fragment-ordered bf16 hi/lo arrays.
// Layout: Wf[(c*4 + tt)*64 + lane] (uint4); lane holds W[16tt+(lane&15)]
// [c*32 + (lane>>4)*8 + j], j=0..7 — exactly the mfma_16x16x32_bf16 B frag.
// Also zeroes the phase23 completion counter (re-poisoned each iteration).
// NOTE (R3 post-mortem): fusing this into gemm regressed 56 µs — on-the-fly
// W split pushed gemm to the 256-VGPR cap (spills) and de-coalesced W loads.
// Keep the pre-pass: packed Wf loads are wave-contiguous 1 KB.
// ---------------------------------------------------------------------------
__global__ __launch_bounds__(256)
void wconv_kernel(const float* __restrict__ W,
                  uint4* __restrict__ Wfh, uint4* __restrict__ Wfl,
                  unsigned* __restrict__ ctr) {
    if (blockIdx.x == 0 && threadIdx.x == 0) *ctr = 0u;
    const int g    = blockIdx.x * 256 + threadIdx.x;   // 0..159999
    const int lane = g & 63;
    const int tt   = (g >> 6) & 3;
    const int c    = g >> 8;
    const int ln = lane & 15, qd = lane >> 4;
    const float* src = W + (size_t)(16 * tt + ln) * V_ + c * 32 + qd * 8;
    const float4 a = *(const float4*)src;
    const float4 b = *(const float4*)(src + 4);
    uint4 h, l; split8(a, b, h, l);
    Wfh[g] = h; Wfl[g] = l;
}

// ---------------------------------------------------------------------------
// gemm3: barrier-free, LDS-free. Block = 4 waves x 64 M-rows = 256 rows, all
// waves share one K-chunk (same W frags -> L1 reuse x4). Per wave per k32:
// 4 A-frags split hi/lo + 8 shared W frags -> 48 MFMAs vs 16 VMEM loads.
// KSPLIT=12: 21x12 = 252 blocks = one co-resident round on 256 CUs (no
// 2nd-round tail); in-flight 4 waves x 16KB/CU >> BW*latency, stays HBM-bound.
// Ragged chunks (11x52 + 1x53) via the clamp/dummy-reload tail.
// Measured 617 µs total (R2); gemm ~88 µs vs 71 µs spec floor on 450 MB
// compulsory traffic = 81% BW efficiency — same as the harness's own fills.
// ---------------------------------------------------------------------------
__global__ __launch_bounds__(256, 2)
void gemm3_kernel(const float* __restrict__ sup,
                  const float* __restrict__ tgtim,
                  const uint4* __restrict__ Wfh,
                  const uint4* __restrict__ Wfl,
                  float* __restrict__ Ep) {
    const int bmx = blockIdx.x;         // 0..20 (M-block of 256 rows)
    const int bk  = blockIdx.y;         // 0..11 (K-split)
    const int t = threadIdx.x;
    const int w = t >> 6, lane = t & 63;
    const int ln = lane & 15, qd = lane >> 4;
    const int mrow0 = bmx * 256 + w * 64;   // wave's 64-row block

    // 5120 = 20*256: blocks 0..19 fully support, block 20 fully target.
    const float* xbase = (mrow0 < B_*S_)
        ? (sup   + (size_t)mrow0 * V_)
        : (tgtim + (size_t)(mrow0 - B_*S_) * V_);
    const float* xr0 = xbase + (size_t)ln * V_ + qd * 8;
    const float* xr1 = xr0 + (size_t)16 * V_;
    const float* xr2 = xr1 + (size_t)16 * V_;
    const float* xr3 = xr2 + (size_t)16 * V_;
    const uint4* wbh = Wfh + lane;
    const uint4* wbl = Wfl + lane;

    const int c0 = bk * KCH;
    const int nk = (bk == KSPLIT - 1) ? (NK32 - KCH * (KSPLIT - 1)) : KCH; // 53 : 52

    f32x4 acc[4][4];
#pragma unroll
    for (int i = 0; i < 4; ++i)
#pragma unroll
        for (int j = 0; j < 4; ++j) acc[i][j] = (f32x4){0.f, 0.f, 0.f, 0.f};

    float4 aA[4][2], aB[4][2];
    uint4 whA[4], wlA[4], whB[4], wlB[4];

#define LDA(buf, c) do {                                                      \
    const size_t off_ = (size_t)(c) * 32;                                     \
    buf[0][0] = *(const float4*)(xr0 + off_);                                 \
    buf[0][1] = *(const float4*)(xr0 + off_ + 4);                             \
    buf[1][0] = *(const float4*)(xr1 + off_);                                 \
    buf[1][1] = *(const float4*)(xr1 + off_ + 4);                             \
    buf[2][0] = *(const float4*)(xr2 + off_);                                 \
    buf[2][1] = *(const float4*)(xr2 + off_ + 4);                             \
    buf[3][0] = *(const float4*)(xr3 + off_);                                 \
    buf[3][1] = *(const float4*)(xr3 + off_ + 4);                             \
} while (0)

#define LDW(bh_, bl_, c) do {                                                 \
    const uint4* ph_ = wbh + (size_t)(c) * 256;                               \
    const uint4* pl_ = wbl + (size_t)(c) * 256;                               \
    _Pragma("unroll")                                                         \
    for (int tt = 0; tt < 4; ++tt) { bh_[tt] = ph_[tt*64]; bl_[tt] = pl_[tt*64]; } \
} while (0)

#define STEP(abuf, bh_, bl_) do {                                             \
    _Pragma("unroll")                                                         \
    for (int af = 0; af < 4; ++af) {                                          \
        uint4 hu_, lu_; split8(abuf[af][0], abuf[af][1], hu_, lu_);           \
        const bf16x8 ah_ = *(const bf16x8*)&hu_;                              \
        const bf16x8 al_ = *(const bf16x8*)&lu_;                              \
        _Pragma("unroll")                                                     \
        for (int tt = 0; tt < 4; ++tt) {                                      \
            const bf16x8 bh2_ = *(const bf16x8*)&bh_[tt];                     \
            const bf16x8 bl2_ = *(const bf16x8*)&bl_[tt];                     \
            acc[af][tt] = __builtin_amdgcn_mfma_f32_16x16x32_bf16(ah_, bh2_, acc[af][tt], 0, 0, 0); \
            acc[af][tt] = __builtin_amdgcn_mfma_f32_16x16x32_bf16(ah_, bl2_, acc[af][tt], 0, 0, 0); \
            acc[af][tt] = __builtin_amdgcn_mfma_f32_16x16x32_bf16(al_, bh2_, acc[af][tt], 0, 0, 0); \
        }                                                                     \
    }                                                                         \
} while (0)

    LDA(aA, c0); LDW(whA, wlA, c0);
    int i = 0;
#pragma unroll 1
    for (; i + 2 <= nk; i += 2) {
        const int c1 = c0 + i + 1;
        LDA(aB, c1); LDW(whB, wlB, c1);
        STEP(aA, whA, wlA);
        const int c2 = c0 + ((i + 2 < nk) ? (i + 2) : (i + 1));  // clamp: dummy reload
        LDA(aA, c2); LDW(whA, wlA, c2);
        STEP(aB, whB, wlB);
    }
    if (i < nk) STEP(aA, whA, wlA);   // odd-nk tail (bk==11, nk=53)

#undef LDA
#undef LDW
#undef STEP

    // C/D layout (m89/m91): col(lane&15)=n, row((lane>>4)*4+reg)=m
    float* dst = Ep + ((size_t)bk * MTOT + mrow0 + qd * 4) * D_ + ln;
#pragma unroll
    for (int af = 0; af < 4; ++af)
#pragma unroll
        for (int tt = 0; tt < 4; ++tt)
#pragma unroll
            for (int r = 0; r < 4; ++r)
                dst[(size_t)(af * 16 + r) * D_ + 16 * tt] = acc[af][tt][r];
}

// ---------------------------------------------------------------------------
// phase23: fused K-split reduce + distance + softmax + preds + argmax + CE,
// plus final reduction done by the last block (atomic-counter pattern).
// Block b: 256 threads sum the 21 relevant rows across 12 partials into LDS,
// then wave 0 runs the verified phase2 math. Last block runs final reduce.
// ---------------------------------------------------------------------------
__global__ __launch_bounds__(256)
void phase23_kernel(const float* __restrict__ Ep,
                    const float* __restrict__ bias,
                    const float* __restrict__ onehot,
                    const int*   __restrict__ ty_,
                    float* __restrict__ res,
                    unsigned* __restrict__ ctr,
                    float* __restrict__ out) {
    const int b = blockIdx.x;
    const int t = threadIdx.x;
    __shared__ float sm[21 * 64];
    const size_t stride = (size_t)MTOT * D_;

#pragma unroll
    for (int base = 0; base < 21 * 64; base += 256) {
        const int idx = base + t;
        if (idx < 21 * 64) {
            const int row = idx >> 6, d = idx & 63;
            const size_t grow = (row < S_) ? ((size_t)b * S_ + row)
                                           : ((size_t)(B_ * S_) + b);
            const float* p0 = Ep + grow * D_ + d;
            float s = 0.f;
#pragma unroll
            for (int p = 0; p < KSPLIT; ++p) s += p0[(size_t)p * stride];
            sm[idx] = s;
        }
    }
    __syncthreads();

    if (t < 64) {
        const int d = t;
        const float bv = bias[d];

        float supv[S_];
#pragma unroll
        for (int s = 0; s < S_; ++s) supv[s] = sm[s * 64 + d] + bv;
        float tg = sm[S_ * 64 + d] + bv;

        float sims[S_];
#pragma unroll
        for (int s = 0; s < S_; ++s) {
            float q = supv[s] * supv[s];
            float r = supv[s] * tg;
#pragma unroll
            for (int off = 32; off; off >>= 1) {
                q += __shfl_xor(q, off);
                r += __shfl_xor(r, off);
            }
            sims[s] = r * rsqrtf(fmaxf(q, 1e-10f));
        }

        float mx = sims[0];
#pragma unroll
        for (int s = 1; s < S_; ++s) mx = fmaxf(mx, sims[s]);
        float se = 0.f;
#pragma unroll
        for (int s = 0; s < S_; ++s) { sims[s] = expf(sims[s] - mx); se += sims[s]; }
        const float inv = 1.f / se;

        float pc = -INFINITY;
        if (d < C_) {
            pc = 0.f;
#pragma unroll
            for (int s = 0; s < S_; ++s)
                pc += sims[s] * inv * onehot[((size_t)b * S_ + s) * C_ + d];
        }

        float v = pc;
        int idx = (d < C_) ? d : (1 << 30);
#pragma unroll
        for (int off = 32; off; off >>= 1) {
            const float ov = __shfl_xor(v, off);
            const int   oi = __shfl_xor(idx, off);
            if (ov > v || (ov == v && oi < idx)) { v = ov; idx = oi; }
        }
        float e = (d < C_) ? expf(pc - v) : 0.f;
#pragma unroll
        for (int off = 32; off; off >>= 1) e += __shfl_xor(e, off);
        const float lse = v + logf(e);

        const int ty = ty_[b];
        const float pty = __shfl(pc, ty);

        if (d == 0) {
            res[b]      = (idx == ty) ? 1.f : 0.f;
            res[B_ + b] = lse - pty;
        }
    }

    // Last-block final reduction (rocPRIM pattern): release fence -> counter;
    // last block acquires and reduces all per-sample results.
    __threadfence();
    __shared__ unsigned lastv;
    if (t == 0) lastv = atomicAdd(ctr, 1u);
    __syncthreads();
    if (lastv == (unsigned)(B_ - 1)) {
        __threadfence();
        if (t < 64) {
            float c = 0.f, l = 0.f;
#pragma unroll
            for (int i = 0; i < 4; ++i) {
                c += res[t + 64 * i];
                l += res[B_ + t + 64 * i];
            }
#pragma unroll
            for (int off = 32; off; off >>= 1) {
                c += __shfl_xor(c, off);
                l += __shfl_xor(l, off);
            }
            if (t == 0) {
                out[0] = c * (1.f / 256.f);
                out[1] = l * (1.f / 256.f);
            }
        }
    }
}

extern "C" void kernel_launch(void* const* d_in, const int* in_sizes, int n_in,
                              void* d_out, int out_size, void* d_ws, size_t ws_size,
                              hipStream_t stream) {
    const float* sup    = (const float*)d_in[0];
    const float* onehot = (const float*)d_in[1];
    const float* tgtim  = (const float*)d_in[2];
    const int*   ty     = (const int*)  d_in[3];
    const float* W      = (const float*)d_in[4];
    const float* bias   = (const float*)d_in[5];

    // ws layout: Ep [12][5376][64] f32 | res [2][256] f32 | ctr (16B pad) |
    //            Wfh | Wfl (2.56MB each)
    float* Ep  = (float*)d_ws;
    float* res = Ep + (size_t)KSPLIT * MTOT * D_;
    unsigned* ctr = (unsigned*)(res + 512);
    uint4* Wfh = (uint4*)(res + 512 + 4);
    uint4* Wfl = Wfh + (size_t)NK32 * 4 * 64;
    float* out = (float*)d_out;

    wconv_kernel<<<625, 256, 0, stream>>>(W, Wfh, Wfl, ctr);
    gemm3_kernel<<<dim3(21, KSPLIT), 256, 0, stream>>>(sup, tgtim, Wfh, Wfl, Ep);
    phase23_kernel<<<B_, 256, 0, stream>>>(Ep, bias, onehot, ty, res, ctr, out);
}